// Round 3
// baseline (16161.702 us; speedup 1.0000x reference)
//
#include <hip/hip_runtime.h>
#include <cstdint>
#include <cstddef>

// LSTM T=8192, I=256, H=1024. Persistent-WG dataflow, flag-free design:
//  - 64 WGs x 256 threads (1 WG/CU); WG w owns hidden units [16w,16w+16)
//    -> 64 gate rows (i,f,g,o x 16 units). Cell update is WG-local.
//  - Weights [W_hh | W_ih] held in VGPRs as fp16 pairs (160 u32/lane).
//    lane = local row (gate = l>>4, unit = l&15); wave = 320-col slice of
//    z = [h (1024) | x (256)].
//  - Cross-WG h exchange via SELF-VALIDATING words: h stored as fp32 with
//    the 2 mantissa LSBs replaced by (t & 3). Readers poll the data words
//    directly until every tag matches (t-1)&3 -> detection IS data arrival;
//    no flags, no release/acquire fences, ONE MALL round trip per step.
//  - Ring depth 2 (slot = t&1, tag = t&3). Per-location coherence of relaxed
//    agent atomics makes init/poison aliasing impossible: memset value 0xAA
//    has tag 2; the first tag-2 expectation (t=3, slot 0) can only be polled
//    by a thread that already observed the t=0 write (tag 0) of that word.
//  - Per step: wave1 stages x[t] (hides under poll); all threads poll their
//    4 h words; pack fp16 -> LDS; broadcast ds_read_b128 + v_dot2 matvec;
//    LDS cross-wave reduce; wave0 gates + tagged h store; wave1 (round-robin
//    WG) does the W_out projection for step t-1 off the critical path.

#define T_STEPS 8192
#define IDIM 256
#define HDIM 1024
#define NWG 64
#define TPB 256

typedef _Float16 h2_t __attribute__((ext_vector_type(2)));

#if defined(__has_builtin)
#if __has_builtin(__builtin_amdgcn_fdot2)
#define HAS_FDOT2 1
#endif
#endif

__device__ __forceinline__ float fdot2(uint32_t a, uint32_t b, float c) {
#ifdef HAS_FDOT2
  return __builtin_amdgcn_fdot2(__builtin_bit_cast(h2_t, a),
                                __builtin_bit_cast(h2_t, b), c, false);
#else
  const h2_t av = __builtin_bit_cast(h2_t, a);
  const h2_t bv = __builtin_bit_cast(h2_t, b);
  c = fmaf((float)av[0], (float)bv[0], c);
  c = fmaf((float)av[1], (float)bv[1], c);
  return c;
#endif
}
__device__ __forceinline__ uint32_t packf16(float a, float b) {
  h2_t v;
  v[0] = (_Float16)a;
  v[1] = (_Float16)b;
  return __builtin_bit_cast(uint32_t, v);
}
__device__ __forceinline__ float sigmoidf_(float x) {
  return 1.0f / (1.0f + __expf(-x));
}
__device__ __forceinline__ float tanhf_(float x) {
  return 1.0f - 2.0f / (1.0f + __expf(2.0f * x));
}

__global__ __launch_bounds__(TPB, 1) void lstm_persistent(
    const float* __restrict__ seq, const float* __restrict__ Wih,
    const float* __restrict__ Whh, const float* __restrict__ bih,
    const float* __restrict__ bhh, const float* __restrict__ Wout,
    const float* __restrict__ bout, float* __restrict__ out,
    uint32_t* __restrict__ ring) {
  const int wg = blockIdx.x;
  const int tid = threadIdx.x;
  const int w = tid >> 6;  // wave 0..3 (col slice)
  const int l = tid & 63;  // lane = local row

  __shared__ uint32_t zbuf[640];  // z=[h(512 u32)|x(128 u32)] as fp16 pairs
  __shared__ float red[4][64];    // cross-wave partial sums
  __shared__ uint32_t wlds[512];  // W_out as fp16 pairs

  // Stage W_out into LDS (fp16 pairs). 256 threads x 4 floats.
  {
    float4 wv = *(const float4*)(Wout + tid * 4);
    wlds[tid * 2] = packf16(wv.x, wv.y);
    wlds[tid * 2 + 1] = packf16(wv.z, wv.w);
  }
  const float b_out0 = bout[0];

  // Load this lane's weight slice into registers as fp16 pairs.
  // global row: gate*H + wg*16 + unit  (PyTorch gate order i,f,g,o)
  const int grow = (l >> 4) * HDIM + wg * 16 + (l & 15);
  const float bias_l = bih[grow] + bhh[grow];
  const float* whrow = Whh + (size_t)grow * HDIM;
  const float* wirow = Wih + (size_t)grow * IDIM;
  const int cbase = w * 320;
  uint32_t wreg[160];
#pragma unroll
  for (int j = 0; j < 160; ++j) {
    const int c = cbase + 2 * j;  // even; never straddles the 1024 boundary
    float a, b;
    if (c < HDIM) {
      a = whrow[c];
      b = whrow[c + 1];
    } else {
      a = wirow[c - HDIM];
      b = wirow[c - HDIM + 1];
    }
    wreg[j] = packf16(a, b);
  }

  float c_st = 0.0f;  // cell state (meaningful on wave 0, lanes<16)

  for (int t = 0; t <= T_STEPS; ++t) {
    __syncthreads();  // zbuf from previous iteration no longer in use

    // Stage x[t] early (wave 1) so its latency hides under the h poll.
    if (t < T_STEPS && tid >= 64 && tid < 128) {
      const int q = tid - 64;
      float4 xv = *(const float4*)(seq + (size_t)t * IDIM + q * 4);
      zbuf[512 + q * 2] = packf16(xv.x, xv.y);
      zbuf[512 + q * 2 + 1] = packf16(xv.z, xv.w);
    }

    if (t > 0) {
      // Poll this thread's 4 h words of step t-1 until tags match.
      const int ps = (t - 1) & 1;
      const uint32_t tg = (uint32_t)((t - 1) & 3);
      const uint64_t want = (uint64_t)tg * 0x0000000100000001ull;
      const uint64_t msk = 0x0000000300000003ull;
      const uint64_t* hp = (const uint64_t*)(ring + ps * HDIM + tid * 4);
      uint64_t v0, v1;
      int guard = 0;
      for (;;) {
        v0 = __hip_atomic_load(hp + 0, __ATOMIC_RELAXED, __HIP_MEMORY_SCOPE_AGENT);
        v1 = __hip_atomic_load(hp + 1, __ATOMIC_RELAXED, __HIP_MEMORY_SCOPE_AGENT);
        if (((v0 & msk) == want) && ((v1 & msk) == want)) break;
        if (++guard > (1 << 22)) break;  // safety: never hang the harness
      }
      const float a0 = __uint_as_float((uint32_t)v0);
      const float a1 = __uint_as_float((uint32_t)(v0 >> 32));
      const float a2 = __uint_as_float((uint32_t)v1);
      const float a3 = __uint_as_float((uint32_t)(v1 >> 32));
      zbuf[tid * 2] = packf16(a0, a1);
      zbuf[tid * 2 + 1] = packf16(a2, a3);
    } else {
      zbuf[tid * 2] = 0u;  // h[-1] = 0
      zbuf[tid * 2 + 1] = 0u;
    }
    __syncthreads();

    if (t < T_STEPS) {
      // Matvec: this wave's 320-col slice, broadcast LDS reads.
      float ac0 = 0.f, ac1 = 0.f, ac2 = 0.f, ac3 = 0.f;
      const uint32_t* zb = zbuf + w * 160;
#pragma unroll
      for (int jj = 0; jj < 40; ++jj) {
        const uint4 zv = *(const uint4*)(zb + jj * 4);  // ds_read_b128 broadcast
        ac0 = fdot2(wreg[jj * 4 + 0], zv.x, ac0);
        ac1 = fdot2(wreg[jj * 4 + 1], zv.y, ac1);
        ac2 = fdot2(wreg[jj * 4 + 2], zv.z, ac2);
        ac3 = fdot2(wreg[jj * 4 + 3], zv.w, ac3);
      }
      red[w][l] = (ac0 + ac1) + (ac2 + ac3);
      __syncthreads();

      if (w == 0) {
        const float g = red[0][l] + red[1][l] + red[2][l] + red[3][l] + bias_l;
        const int uu = l & 15;
        const float gi = __shfl(g, uu);
        const float gf = __shfl(g, uu + 16);
        const float gg = __shfl(g, uu + 32);
        const float go = __shfl(g, uu + 48);
        if (l < 16) {
          const float is = sigmoidf_(gi);
          const float fs = sigmoidf_(gf);
          const float gt = tanhf_(gg);
          const float os = sigmoidf_(go);
          c_st = fs * c_st + is * gt;
          const float hv = os * tanhf_(c_st);
          // Tagged store: 2 mantissa LSBs carry (t & 3).
          const uint32_t hb = (__float_as_uint(hv) & ~3u) | (uint32_t)(t & 3);
          __hip_atomic_store(ring + (t & 1) * HDIM + wg * 16 + l, hb,
                             __ATOMIC_RELAXED, __HIP_MEMORY_SCOPE_AGENT);
        }
      }
    }

    // Output for step t-1 on wave 1, round-robin across WGs — off the
    // critical path (wave 0 is doing gates). zbuf h-region holds h[t-1]
    // until the next loop-top barrier.
    if (t > 0 && w == 1 && ((t - 1) & (NWG - 1)) == wg) {
      float o0 = 0.f, o1 = 0.f;
#pragma unroll
      for (int j = 0; j < 8; j += 2) {
        o0 = fdot2(wlds[l * 8 + j], zbuf[l * 8 + j], o0);
        o1 = fdot2(wlds[l * 8 + j + 1], zbuf[l * 8 + j + 1], o1);
      }
      float o = o0 + o1;
#pragma unroll
      for (int off = 32; off >= 1; off >>= 1) o += __shfl_xor(o, off);
      if (l == 0) out[t - 1] = sigmoidf_(o + b_out0);
    }
  }
}

extern "C" void kernel_launch(void* const* d_in, const int* in_sizes, int n_in,
                              void* d_out, int out_size, void* d_ws, size_t ws_size,
                              hipStream_t stream) {
  const float* seq = (const float*)d_in[0];
  const float* Wih = (const float*)d_in[1];
  const float* Whh = (const float*)d_in[2];
  const float* bih = (const float*)d_in[3];
  const float* bhh = (const float*)d_in[4];
  const float* Wout = (const float*)d_in[5];
  const float* bout = (const float*)d_in[6];

  uint32_t* ring = (uint32_t*)d_ws;  // 2 * 1024 u32 = 8 KB

  // Init ring to 0xAA bytes (tag 2): proven alias-free vs the tag schedule.
  // Needed because the very first (correctness) call may see arbitrary ws.
  hipMemsetAsync(d_ws, 0xAA, 2 * HDIM * sizeof(uint32_t), stream);

  lstm_persistent<<<NWG, TPB, 0, stream>>>(seq, Wih, Whh, bih, bhh, Wout, bout,
                                           (float*)d_out, ring);
}